// Round 1
// baseline (1247.686 us; speedup 1.0000x reference)
//
#include <hip/hip_runtime.h>
#include <hip/hip_bf16.h>

#define S_DIM 1024
#define R_DIM 512
#define C_DIM 256
#define H_DIM 8
#define CH_DIM 32
#define BS 64
#define SB (S_DIM / BS)   // 16

typedef __attribute__((ext_vector_type(8))) short short8;
typedef __attribute__((ext_vector_type(4))) float floatx4;

__device__ inline float bf2f(unsigned short u) {
    return __uint_as_float(((unsigned int)u) << 16);
}
__device__ inline unsigned short f2bf(float f) {
    unsigned int x = __float_as_uint(f);
    unsigned int r = ((x >> 16) & 1u) + 0x7fffu;
    return (unsigned short)((x + r) >> 16);
}

// ---------------- prep: build transposed bf16 weight copies ----------------
__global__ __launch_bounds__(256) void prep_kernel(
        const float* __restrict__ Wk, const float* __restrict__ Wv,
        const float* __restrict__ Wg, const float* __restrict__ Wf,
        unsigned short* __restrict__ wgT, unsigned short* __restrict__ wfhi,
        unsigned short* __restrict__ wflo, unsigned short* __restrict__ wkvT) {
    int b = blockIdx.x;    // output column index (0..255)
    int k = threadIdx.x;   // k index (0..255)
    wgT[b * 256 + k] = f2bf(Wg[k * 256 + b]);
    float w = Wf[k * 256 + b];
    unsigned short hi = f2bf(w);
    wfhi[b * 256 + k] = hi;
    wflo[b * 256 + k] = f2bf(w - bf2f(hi));
    if (b < 64) {
        float t = (b < 32) ? Wk[k * 32 + b] : Wv[k * 32 + (b - 32)];
        wkvT[b * 256 + k] = f2bf(t);
    }
}

// ------------- stage 64 LayerNorm'd rows (bf16) into LDS [64][264] ---------
__device__ inline void stage_xn(const float* __restrict__ x,
                                const float* __restrict__ lns,
                                const float* __restrict__ lnb,
                                int s0, int r, unsigned short* xn) {
    const int t = threadIdx.x;
    const int row = t >> 2;        // 0..63
    const int q = t & 3;           // quarter of the row
    const size_t base = ((size_t)(s0 + row) * R_DIM + r) * C_DIM + q * 64;
    const float4* gp = reinterpret_cast<const float4*>(x + base);
    float4 v[16];
    float sum = 0.f, sq = 0.f;
#pragma unroll
    for (int i = 0; i < 16; i++) {
        v[i] = gp[i];
        sum += v[i].x + v[i].y + v[i].z + v[i].w;
        sq  += v[i].x * v[i].x + v[i].y * v[i].y + v[i].z * v[i].z + v[i].w * v[i].w;
    }
    sum += __shfl_xor(sum, 1); sq += __shfl_xor(sq, 1);
    sum += __shfl_xor(sum, 2); sq += __shfl_xor(sq, 2);
    float mu = sum * (1.f / 256.f);
    float var = sq * (1.f / 256.f) - mu * mu;
    float rs = rsqrtf(var + 1e-5f);
    const float4* sp = reinterpret_cast<const float4*>(lns + q * 64);
    const float4* bp = reinterpret_cast<const float4*>(lnb + q * 64);
    unsigned short* wp = xn + row * 264 + q * 64;
#pragma unroll
    for (int i = 0; i < 16; i++) {
        float4 g = sp[i];
        float4 bb = bp[i];
        ushort4 o;
        o.x = f2bf((v[i].x - mu) * rs * g.x + bb.x);
        o.y = f2bf((v[i].y - mu) * rs * g.y + bb.y);
        o.z = f2bf((v[i].z - mu) * rs * g.z + bb.z);
        o.w = f2bf((v[i].w - mu) * rs * g.w + bb.w);
        *reinterpret_cast<ushort4*>(wp + i * 4) = o;
    }
}

// ---------------- K1: k/v + masked column sums -----------------------------
__global__ __launch_bounds__(256) void k1_kernel(
        const float* __restrict__ x, const float* __restrict__ mask,
        const float* __restrict__ lns, const float* __restrict__ lnb,
        const unsigned short* __restrict__ wkvT, unsigned short* __restrict__ kv,
        float* __restrict__ qsum, float* __restrict__ msum) {
    __shared__ unsigned short xn[64 * 264];
    __shared__ float mk[64];
    const int sblk = blockIdx.x, r = blockIdx.y;
    const int s0 = sblk * BS;
    const int t = threadIdx.x;
    stage_xn(x, lns, lnb, s0, r, xn);
    if (t < 64) mk[t] = mask[(size_t)(s0 + t) * R_DIM + r];
    __syncthreads();

    // MFMA: wave w -> rows 16w..16w+15, cols 0..63 (= [k | v])
    const int w = t >> 6, l = t & 63;
    const int lr = l & 15, lk = (l >> 4) * 8;
    floatx4 acc[4] = {};
    const unsigned short* arow = xn + (w * 16 + lr) * 264;
#pragma unroll
    for (int kk = 0; kk < 256; kk += 32) {
        short8 a = *reinterpret_cast<const short8*>(arow + kk + lk);
#pragma unroll
        for (int n = 0; n < 4; n++) {
            short8 b = *reinterpret_cast<const short8*>(wkvT + (n * 16 + lr) * 256 + kk + lk);
            acc[n] = __builtin_amdgcn_mfma_f32_16x16x32_bf16(a, b, acc[n], 0, 0, 0);
        }
    }
    unsigned short* kvp = kv + ((size_t)r * S_DIM + s0) * 64;
#pragma unroll
    for (int n = 0; n < 4; n++) {
        int col = n * 16 + lr;
#pragma unroll
        for (int i = 0; i < 4; i++) {
            int row = w * 16 + (l >> 4) * 4 + i;
            kvp[(size_t)row * 64 + col] = f2bf(acc[n][i]);
        }
    }
    // masked column sums over the 64 rows
    float cs = 0.f;
    const int c = t;
#pragma unroll 8
    for (int row = 0; row < 64; row++) cs += bf2f(xn[row * 264 + c]) * mk[row];
    qsum[((size_t)r * SB + sblk) * 256 + c] = cs;
    if (t < 64) {
        float m = mk[t];
#pragma unroll
        for (int off = 32; off; off >>= 1) m += __shfl_xor(m, off);
        if (t == 0) msum[r * SB + sblk] = m;
    }
}

// ---------------- K2: q_avg, q, softmax, o ---------------------------------
__global__ __launch_bounds__(256) void k2_kernel(
        const float* __restrict__ mask, const float* __restrict__ Wq,
        const float* __restrict__ qsum, const float* __restrict__ msum,
        const unsigned short* __restrict__ kv, float* __restrict__ oout) {
    __shared__ float qavg[256];
    __shared__ float qh[256];
    __shared__ float lg[8][1024];
    __shared__ float red[8];
    const int r = blockIdx.x;
    const int t = threadIdx.x;

    float ms = 0.f;
#pragma unroll
    for (int i = 0; i < SB; i++) ms += msum[r * SB + i];
    float inv = 1.f / (ms + 1e-10f);
    float qs = 0.f;
#pragma unroll
    for (int i = 0; i < SB; i++) qs += qsum[((size_t)r * SB + i) * 256 + t];
    qavg[t] = qs * inv;
    __syncthreads();

    float accq = 0.f;
    for (int c = 0; c < 256; c++) accq += qavg[c] * Wq[c * 256 + t];
    qh[t] = accq * 0.17677669529663687f;   // CH^-0.5
    __syncthreads();

    const unsigned short* kvr = kv + (size_t)r * S_DIM * 64;
#pragma unroll
    for (int i = 0; i < 4; i++) {
        int s = i * 256 + t;
        float bias = 1e9f * (mask[(size_t)s * R_DIM + r] - 1.f);
        const unsigned int* kp = reinterpret_cast<const unsigned int*>(kvr + (size_t)s * 64);
        float kvals[32];
#pragma unroll
        for (int j = 0; j < 16; j++) {
            unsigned int u = kp[j];
            kvals[2 * j]     = __uint_as_float(u << 16);
            kvals[2 * j + 1] = __uint_as_float(u & 0xffff0000u);
        }
#pragma unroll
        for (int h = 0; h < 8; h++) {
            float d = 0.f;
#pragma unroll
            for (int ch = 0; ch < 32; ch++) d += qh[h * 32 + ch] * kvals[ch];
            lg[h][s] = d + bias;
        }
    }
    __syncthreads();

    for (int h = 0; h < 8; h++) {
        float mx = -1e30f;
#pragma unroll
        for (int i = 0; i < 4; i++) mx = fmaxf(mx, lg[h][i * 256 + t]);
        for (int off = 32; off; off >>= 1) mx = fmaxf(mx, __shfl_xor(mx, off));
        if ((t & 63) == 0) red[t >> 6] = mx;
        __syncthreads();
        mx = fmaxf(fmaxf(red[0], red[1]), fmaxf(red[2], red[3]));
        float sm = 0.f;
#pragma unroll
        for (int i = 0; i < 4; i++) {
            float e = __expf(lg[h][i * 256 + t] - mx);
            lg[h][i * 256 + t] = e;
            sm += e;
        }
        for (int off = 32; off; off >>= 1) sm += __shfl_xor(sm, off);
        if ((t & 63) == 0) red[4 + (t >> 6)] = sm;
        __syncthreads();
        sm = red[4] + red[5] + red[6] + red[7];
        float isv = 1.f / sm;
#pragma unroll
        for (int i = 0; i < 4; i++) lg[h][i * 256 + t] *= isv;
        __syncthreads();
    }

    const int h = t >> 5, ch = t & 31;
    const unsigned short* vp = kvr + 32 + ch;
    float o = 0.f;
#pragma unroll 4
    for (int s = 0; s < 1024; s++) o += lg[h][s] * bf2f(vp[(size_t)s * 64]);
    oout[r * 256 + t] = o;
}

// ---------------- K3: gate + final matmul (bf16x3) -------------------------
__global__ __launch_bounds__(256) void k3_kernel(
        const float* __restrict__ x, const float* __restrict__ lns,
        const float* __restrict__ lnb, const unsigned short* __restrict__ wgT,
        const unsigned short* __restrict__ wfhi, const unsigned short* __restrict__ wflo,
        const float* __restrict__ oin, const float* __restrict__ bg,
        const float* __restrict__ bfv, float* __restrict__ out) {
    __shared__ unsigned short xa[64 * 264];   // xn, later A2 hi
    __shared__ unsigned short xb[64 * 264];   // A2 lo
    const int sblk = blockIdx.x, r = blockIdx.y;
    const int s0 = sblk * BS;
    const int t = threadIdx.x;
    stage_xn(x, lns, lnb, s0, r, xa);
    __syncthreads();

    const int w = t >> 6, l = t & 63;
    const int lr = l & 15, lk4 = (l >> 4);
    const int colbase = w * 64;

    float bgv[4], ov[4];
#pragma unroll
    for (int n = 0; n < 4; n++) {
        int col = colbase + n * 16 + lr;
        bgv[n] = bg[col];
        ov[n] = oin[r * 256 + col];
    }

    floatx4 acc[4][4] = {};
#pragma unroll
    for (int kk = 0; kk < 256; kk += 32) {
        short8 a[4];
#pragma unroll
        for (int m = 0; m < 4; m++)
            a[m] = *reinterpret_cast<const short8*>(xa + (m * 16 + lr) * 264 + kk + lk4 * 8);
#pragma unroll
        for (int n = 0; n < 4; n++) {
            short8 b = *reinterpret_cast<const short8*>(wgT + (size_t)(colbase + n * 16 + lr) * 256 + kk + lk4 * 8);
#pragma unroll
            for (int m = 0; m < 4; m++)
                acc[m][n] = __builtin_amdgcn_mfma_f32_16x16x32_bf16(a[m], b, acc[m][n], 0, 0, 0);
        }
    }
    __syncthreads();   // everyone done reading xn

#pragma unroll
    for (int m = 0; m < 4; m++) {
#pragma unroll
        for (int n = 0; n < 4; n++) {
            int col = colbase + n * 16 + lr;
#pragma unroll
            for (int i = 0; i < 4; i++) {
                int row = m * 16 + lk4 * 4 + i;
                float z = acc[m][n][i] + bgv[n];
                float g = 1.f / (1.f + __expf(-z));
                float val = g * ov[n];
                unsigned short hi = f2bf(val);
                xa[row * 264 + col] = hi;
                xb[row * 264 + col] = f2bf(val - bf2f(hi));
            }
        }
    }
    __syncthreads();

    floatx4 acc2[4][4] = {};
#pragma unroll
    for (int kk = 0; kk < 256; kk += 32) {
        short8 ah[4], al[4];
#pragma unroll
        for (int m = 0; m < 4; m++) {
            ah[m] = *reinterpret_cast<const short8*>(xa + (m * 16 + lr) * 264 + kk + lk4 * 8);
            al[m] = *reinterpret_cast<const short8*>(xb + (m * 16 + lr) * 264 + kk + lk4 * 8);
        }
#pragma unroll
        for (int n = 0; n < 4; n++) {
            const size_t boff = (size_t)(colbase + n * 16 + lr) * 256 + kk + lk4 * 8;
            short8 bh = *reinterpret_cast<const short8*>(wfhi + boff);
            short8 bl = *reinterpret_cast<const short8*>(wflo + boff);
#pragma unroll
            for (int m = 0; m < 4; m++) {
                acc2[m][n] = __builtin_amdgcn_mfma_f32_16x16x32_bf16(ah[m], bh, acc2[m][n], 0, 0, 0);
                acc2[m][n] = __builtin_amdgcn_mfma_f32_16x16x32_bf16(ah[m], bl, acc2[m][n], 0, 0, 0);
                acc2[m][n] = __builtin_amdgcn_mfma_f32_16x16x32_bf16(al[m], bh, acc2[m][n], 0, 0, 0);
            }
        }
    }

#pragma unroll
    for (int n = 0; n < 4; n++) {
        int col = colbase + n * 16 + lr;
        float bfc = bfv[col];
#pragma unroll
        for (int m = 0; m < 4; m++) {
#pragma unroll
            for (int i = 0; i < 4; i++) {
                int row = m * 16 + lk4 * 4 + i;
                out[((size_t)(s0 + row) * R_DIM + r) * C_DIM + col] = acc2[m][n][i] + bfc;
            }
        }
    }
}

extern "C" void kernel_launch(void* const* d_in, const int* in_sizes, int n_in,
                              void* d_out, int out_size, void* d_ws, size_t ws_size,
                              hipStream_t stream) {
    const float* x1   = (const float*)d_in[0];
    const float* mask = (const float*)d_in[1];
    const float* lns  = (const float*)d_in[2];
    const float* lnb  = (const float*)d_in[3];
    const float* Wq   = (const float*)d_in[4];
    const float* Wk   = (const float*)d_in[5];
    const float* Wv   = (const float*)d_in[6];
    const float* Wg   = (const float*)d_in[7];
    const float* bg   = (const float*)d_in[8];
    const float* Wf   = (const float*)d_in[9];
    const float* bfv  = (const float*)d_in[10];

    char* ws = (char*)d_ws;
    unsigned short* wgT  = (unsigned short*)(ws);                 // 128 KB
    unsigned short* wfhi = (unsigned short*)(ws + 131072);        // 128 KB
    unsigned short* wflo = (unsigned short*)(ws + 262144);        // 128 KB
    unsigned short* wkvT = (unsigned short*)(ws + 393216);        // 32 KB
    float* qsum = (float*)(ws + 425984);                          // 8 MB
    float* msum = (float*)(ws + 425984 + 8388608);                // 32 KB
    float* oo   = (float*)(ws + 425984 + 8388608 + 32768);        // 512 KB
    // kv scratch lives in d_out (67 MB); K3 overwrites d_out only after K2
    // has consumed kv (same stream => ordered).
    unsigned short* kv = (unsigned short*)d_out;
    float* out = (float*)d_out;

    prep_kernel<<<256, 256, 0, stream>>>(Wk, Wv, Wg, Wf, wgT, wfhi, wflo, wkvT);
    k1_kernel<<<dim3(SB, R_DIM), 256, 0, stream>>>(x1, mask, lns, lnb, wkvT, kv, qsum, msum);
    k2_kernel<<<R_DIM, 256, 0, stream>>>(mask, Wq, qsum, msum, kv, oo);
    k3_kernel<<<dim3(SB, R_DIM), 256, 0, stream>>>(x1, lns, lnb, wgT, wfhi, wflo, oo, bg, bfv, out);
}

// Round 2
// 955.792 us; speedup vs baseline: 1.3054x; 1.3054x over previous
//
#include <hip/hip_runtime.h>
#include <hip/hip_bf16.h>

#define S_DIM 1024
#define R_DIM 512
#define C_DIM 256
#define BS 64
#define SB (S_DIM / BS)   // 16

#define XN_OFF (16u << 20)                       // xn cache at ws+16MB
#define XN_BYTES (512ull * 1024ull * 256ull * 2ull)  // 268435456

typedef __attribute__((ext_vector_type(8))) short short8;
typedef __attribute__((ext_vector_type(8))) unsigned short ushort8v;
typedef __attribute__((ext_vector_type(4))) float floatx4;

__device__ inline float bf2f(unsigned short u) {
    return __uint_as_float(((unsigned int)u) << 16);
}
__device__ inline unsigned short f2bf(float f) {
    unsigned int x = __float_as_uint(f);
    unsigned int r = ((x >> 16) & 1u) + 0x7fffu;
    return (unsigned short)((x + r) >> 16);
}

__device__ inline void async16(unsigned short* lds, const unsigned short* g) {
    __builtin_amdgcn_global_load_lds(
        (const __attribute__((address_space(1))) void*)g,
        (__attribute__((address_space(3))) void*)lds, 16, 0, 0);
}

// ---------------- prep: build transposed bf16 weight copies ----------------
__global__ __launch_bounds__(256) void prep_kernel(
        const float* __restrict__ Wk, const float* __restrict__ Wv,
        const float* __restrict__ Wg, const float* __restrict__ Wf,
        unsigned short* __restrict__ wgT, unsigned short* __restrict__ wfhi,
        unsigned short* __restrict__ wflo, unsigned short* __restrict__ wkvT) {
    int b = blockIdx.x;    // output column index (0..255)
    int k = threadIdx.x;   // k index (0..255)
    wgT[b * 256 + k] = f2bf(Wg[k * 256 + b]);
    float w = Wf[k * 256 + b];
    unsigned short hi = f2bf(w);
    wfhi[b * 256 + k] = hi;
    wflo[b * 256 + k] = f2bf(w - bf2f(hi));
    if (b < 64) {
        float t = (b < 32) ? Wk[k * 32 + b] : Wv[k * 32 + (b - 32)];
        wkvT[b * 256 + k] = f2bf(t);
    }
}

// ------------- stage 64 LayerNorm'd rows (bf16) into LDS [64][264] ---------
// 16-byte LDS writes (row stride 528B = 33 quads -> conflict-free).
// If CACHE, also mirror the bf16 rows to global xnws [s][r][c].
template <int CACHE>
__device__ inline void stage_xn(const float* __restrict__ x,
                                const float* __restrict__ lns,
                                const float* __restrict__ lnb,
                                int s0, int r, unsigned short* xn,
                                unsigned short* __restrict__ xnws) {
    const int t = threadIdx.x;
    const int row = t >> 2;        // 0..63
    const int q = t & 3;           // quarter of the row
    const size_t base = ((size_t)(s0 + row) * R_DIM + r) * C_DIM + q * 64;
    const float4* gp = reinterpret_cast<const float4*>(x + base);
    float4 v[16];
    float sum = 0.f, sq = 0.f;
#pragma unroll
    for (int i = 0; i < 16; i++) {
        v[i] = gp[i];
        sum += v[i].x + v[i].y + v[i].z + v[i].w;
        sq  += v[i].x * v[i].x + v[i].y * v[i].y + v[i].z * v[i].z + v[i].w * v[i].w;
    }
    sum += __shfl_xor(sum, 1); sq += __shfl_xor(sq, 1);
    sum += __shfl_xor(sum, 2); sq += __shfl_xor(sq, 2);
    float mu = sum * (1.f / 256.f);
    float var = sq * (1.f / 256.f) - mu * mu;
    float rs = rsqrtf(var + 1e-5f);
    const float4* sp = reinterpret_cast<const float4*>(lns + q * 64);
    const float4* bp = reinterpret_cast<const float4*>(lnb + q * 64);
    unsigned short* wp = xn + row * 264 + q * 64;
    unsigned short* gw = CACHE ? (xnws + ((size_t)(s0 + row) * R_DIM + r) * C_DIM + q * 64)
                               : nullptr;
#pragma unroll
    for (int i = 0; i < 16; i += 2) {
        float4 g0 = sp[i],     b0 = bp[i];
        float4 g1 = sp[i + 1], b1 = bp[i + 1];
        ushort8v u;
        u[0] = f2bf((v[i].x     - mu) * rs * g0.x + b0.x);
        u[1] = f2bf((v[i].y     - mu) * rs * g0.y + b0.y);
        u[2] = f2bf((v[i].z     - mu) * rs * g0.z + b0.z);
        u[3] = f2bf((v[i].w     - mu) * rs * g0.w + b0.w);
        u[4] = f2bf((v[i + 1].x - mu) * rs * g1.x + b1.x);
        u[5] = f2bf((v[i + 1].y - mu) * rs * g1.y + b1.y);
        u[6] = f2bf((v[i + 1].z - mu) * rs * g1.z + b1.z);
        u[7] = f2bf((v[i + 1].w - mu) * rs * g1.w + b1.w);
        *reinterpret_cast<ushort8v*>(wp + i * 4) = u;
        if (CACHE) *reinterpret_cast<ushort8v*>(gw + i * 4) = u;
    }
}

// ---------------- K1: k/v + masked column sums -----------------------------
template <int CACHE>
__global__ __launch_bounds__(256, 4) void k1_kernel(
        const float* __restrict__ x, const float* __restrict__ mask,
        const float* __restrict__ lns, const float* __restrict__ lnb,
        const unsigned short* __restrict__ wkvT, unsigned short* __restrict__ kv,
        float* __restrict__ qsum, float* __restrict__ msum,
        unsigned short* __restrict__ xnws) {
    __shared__ unsigned short xn[64 * 264];
    __shared__ float mk[64];
    const int sblk = blockIdx.x, r = blockIdx.y;
    const int s0 = sblk * BS;
    const int t = threadIdx.x;
    stage_xn<CACHE>(x, lns, lnb, s0, r, xn, xnws);
    if (t < 64) mk[t] = mask[(size_t)(s0 + t) * R_DIM + r];
    __syncthreads();

    // MFMA: wave w -> rows 16w..16w+15, cols 0..63 (= [k | v])
    const int w = t >> 6, l = t & 63;
    const int lr = l & 15, lk = (l >> 4) * 8;
    floatx4 acc[4] = {};
    const unsigned short* arow = xn + (w * 16 + lr) * 264;
#pragma unroll
    for (int kk = 0; kk < 256; kk += 32) {
        short8 a = *reinterpret_cast<const short8*>(arow + kk + lk);
#pragma unroll
        for (int n = 0; n < 4; n++) {
            short8 b = *reinterpret_cast<const short8*>(wkvT + (n * 16 + lr) * 256 + kk + lk);
            acc[n] = __builtin_amdgcn_mfma_f32_16x16x32_bf16(a, b, acc[n], 0, 0, 0);
        }
    }
    unsigned short* kvp = kv + ((size_t)r * S_DIM + s0) * 64;
#pragma unroll
    for (int n = 0; n < 4; n++) {
        int col = n * 16 + lr;
#pragma unroll
        for (int i = 0; i < 4; i++) {
            int row = w * 16 + (l >> 4) * 4 + i;
            kvp[(size_t)row * 64 + col] = f2bf(acc[n][i]);
        }
    }
    // masked column sums over the 64 rows
    float cs = 0.f;
    const int c = t;
#pragma unroll 8
    for (int row = 0; row < 64; row++) cs += bf2f(xn[row * 264 + c]) * mk[row];
    qsum[((size_t)r * SB + sblk) * 256 + c] = cs;
    if (t < 64) {
        float m = mk[t];
#pragma unroll
        for (int off = 32; off; off >>= 1) m += __shfl_xor(m, off);
        if (t == 0) msum[r * SB + sblk] = m;
    }
}

// ---------------- K2: q_avg, q, softmax, o ---------------------------------
__global__ __launch_bounds__(256) void k2_kernel(
        const float* __restrict__ mask, const float* __restrict__ Wq,
        const float* __restrict__ qsum, const float* __restrict__ msum,
        const unsigned short* __restrict__ kv, float* __restrict__ oout) {
    __shared__ float qavg[256];
    __shared__ float qh[256];
    __shared__ float lg[8][1024];
    __shared__ float red[8];
    __shared__ unsigned short vt[256 * 36];   // v tile, padded rows (72 B)
    const int r = blockIdx.x;
    const int t = threadIdx.x;

    float ms = 0.f;
#pragma unroll
    for (int i = 0; i < SB; i++) ms += msum[r * SB + i];
    float inv = 1.f / (ms + 1e-10f);
    float qs = 0.f;
#pragma unroll
    for (int i = 0; i < SB; i++) qs += qsum[((size_t)r * SB + i) * 256 + t];
    qavg[t] = qs * inv;
    __syncthreads();

    float accq = 0.f;
    for (int c = 0; c < 256; c++) accq += qavg[c] * Wq[c * 256 + t];
    qh[t] = accq * 0.17677669529663687f;   // CH^-0.5
    __syncthreads();

    const unsigned short* kvr = kv + (size_t)r * S_DIM * 64;
#pragma unroll
    for (int i = 0; i < 4; i++) {
        int s = i * 256 + t;
        float bias = 1e9f * (mask[(size_t)s * R_DIM + r] - 1.f);
        const unsigned int* kp = reinterpret_cast<const unsigned int*>(kvr + (size_t)s * 64);
        float kvals[32];
#pragma unroll
        for (int j = 0; j < 16; j++) {
            unsigned int u = kp[j];
            kvals[2 * j]     = __uint_as_float(u << 16);
            kvals[2 * j + 1] = __uint_as_float(u & 0xffff0000u);
        }
#pragma unroll
        for (int h = 0; h < 8; h++) {
            float d = 0.f;
#pragma unroll
            for (int ch = 0; ch < 32; ch++) d += qh[h * 32 + ch] * kvals[ch];
            lg[h][s] = d + bias;
        }
    }
    __syncthreads();

    for (int h = 0; h < 8; h++) {
        float mx = -1e30f;
#pragma unroll
        for (int i = 0; i < 4; i++) mx = fmaxf(mx, lg[h][i * 256 + t]);
        for (int off = 32; off; off >>= 1) mx = fmaxf(mx, __shfl_xor(mx, off));
        if ((t & 63) == 0) red[t >> 6] = mx;
        __syncthreads();
        mx = fmaxf(fmaxf(red[0], red[1]), fmaxf(red[2], red[3]));
        float sm = 0.f;
#pragma unroll
        for (int i = 0; i < 4; i++) {
            float e = __expf(lg[h][i * 256 + t] - mx);
            lg[h][i * 256 + t] = e;
            sm += e;
        }
        for (int off = 32; off; off >>= 1) sm += __shfl_xor(sm, off);
        if ((t & 63) == 0) red[4 + (t >> 6)] = sm;
        __syncthreads();
        sm = red[4] + red[5] + red[6] + red[7];
        float isv = 1.f / sm;
#pragma unroll
        for (int i = 0; i < 4; i++) lg[h][i * 256 + t] *= isv;
        __syncthreads();
    }

    // o = w @ v via LDS-staged v tiles (broadcast reads)
    const int h = t >> 5, ch = t & 31;
    float o = 0.f;
    for (int st = 0; st < 4; st++) {
        __syncthreads();
        {
            const unsigned short* src = kvr + ((size_t)(st * 256 + t)) * 64 + 32;
            ushort4* dst = reinterpret_cast<ushort4*>(vt + t * 36);
#pragma unroll
            for (int j = 0; j < 8; j++)
                dst[j] = *reinterpret_cast<const ushort4*>(src + 4 * j);
        }
        __syncthreads();
#pragma unroll 8
        for (int sl = 0; sl < 256; sl++)
            o += lg[h][st * 256 + sl] * bf2f(vt[sl * 36 + ch]);
    }
    oout[r * 256 + t] = o;
}

// ---------------- K3 (recompute path): gate + final matmul (A-hi only) -----
__global__ __launch_bounds__(256, 4) void k3r_kernel(
        const float* __restrict__ x, const float* __restrict__ lns,
        const float* __restrict__ lnb, const unsigned short* __restrict__ wgT,
        const unsigned short* __restrict__ wfhi, const unsigned short* __restrict__ wflo,
        const float* __restrict__ oin, const float* __restrict__ bg,
        const float* __restrict__ bfv, float* __restrict__ out) {
    __shared__ unsigned short xa[64 * 264];   // xn, later A2 (hi)
    const int sblk = blockIdx.x, r = blockIdx.y;
    const int s0 = sblk * BS;
    const int t = threadIdx.x;
    stage_xn<0>(x, lns, lnb, s0, r, xa, nullptr);
    __syncthreads();

    const int w = t >> 6, l = t & 63;
    const int lr = l & 15, lk4 = (l >> 4);
    const int colbase = w * 64;

    float bgv[4], ov[4];
#pragma unroll
    for (int n = 0; n < 4; n++) {
        int col = colbase + n * 16 + lr;
        bgv[n] = bg[col];
        ov[n] = oin[r * 256 + col];
    }

    floatx4 acc[4][4] = {};
#pragma unroll
    for (int kk = 0; kk < 256; kk += 32) {
        short8 a[4];
#pragma unroll
        for (int m = 0; m < 4; m++)
            a[m] = *reinterpret_cast<const short8*>(xa + (m * 16 + lr) * 264 + kk + lk4 * 8);
#pragma unroll
        for (int n = 0; n < 4; n++) {
            short8 b = *reinterpret_cast<const short8*>(wgT + (size_t)(colbase + n * 16 + lr) * 256 + kk + lk4 * 8);
#pragma unroll
            for (int m = 0; m < 4; m++)
                acc[m][n] = __builtin_amdgcn_mfma_f32_16x16x32_bf16(a[m], b, acc[m][n], 0, 0, 0);
        }
    }
    __syncthreads();   // everyone done reading xn

#pragma unroll
    for (int m = 0; m < 4; m++) {
#pragma unroll
        for (int n = 0; n < 4; n++) {
            int col = colbase + n * 16 + lr;
#pragma unroll
            for (int i = 0; i < 4; i++) {
                int row = m * 16 + lk4 * 4 + i;
                float z = acc[m][n][i] + bgv[n];
                float g = 1.f / (1.f + __expf(-z));
                xa[row * 264 + col] = f2bf(g * ov[n]);
            }
        }
    }
    __syncthreads();

    floatx4 acc2[4][4] = {};
#pragma unroll
    for (int kk = 0; kk < 256; kk += 32) {
        short8 ah[4];
#pragma unroll
        for (int m = 0; m < 4; m++)
            ah[m] = *reinterpret_cast<const short8*>(xa + (m * 16 + lr) * 264 + kk + lk4 * 8);
#pragma unroll
        for (int n = 0; n < 4; n++) {
            const size_t boff = (size_t)(colbase + n * 16 + lr) * 256 + kk + lk4 * 8;
            short8 bh = *reinterpret_cast<const short8*>(wfhi + boff);
            short8 bl = *reinterpret_cast<const short8*>(wflo + boff);
#pragma unroll
            for (int m = 0; m < 4; m++) {
                acc2[m][n] = __builtin_amdgcn_mfma_f32_16x16x32_bf16(ah[m], bh, acc2[m][n], 0, 0, 0);
                acc2[m][n] = __builtin_amdgcn_mfma_f32_16x16x32_bf16(ah[m], bl, acc2[m][n], 0, 0, 0);
            }
        }
    }

#pragma unroll
    for (int n = 0; n < 4; n++) {
        int col = colbase + n * 16 + lr;
        float bfc = bfv[col];
#pragma unroll
        for (int m = 0; m < 4; m++) {
#pragma unroll
            for (int i = 0; i < 4; i++) {
                int row = m * 16 + lk4 * 4 + i;
                out[((size_t)(s0 + row) * R_DIM + r) * C_DIM + col] = acc2[m][n][i] + bfc;
            }
        }
    }
}

// ---------------- K3 (xn-cache path): async-staged, XOR-swizzled LDS -------
__global__ __launch_bounds__(256, 4) void k3c_kernel(
        const unsigned short* __restrict__ xnws, const unsigned short* __restrict__ wgT,
        const unsigned short* __restrict__ wfhi, const unsigned short* __restrict__ wflo,
        const float* __restrict__ oin, const float* __restrict__ bg,
        const float* __restrict__ bfv, float* __restrict__ out) {
    __shared__ unsigned short xa[64 * 256];   // 32 KB, chunk' = chunk ^ (row&7)
    const int sblk = blockIdx.x, r = blockIdx.y;
    const int s0 = sblk * BS;
    const int t = threadIdx.x;
    const int w = t >> 6, l = t & 63;

    // async stage: wave w loads rows 16w..16w+15; LDS linear, source pre-swizzled
    {
        const int c1 = l & 31;
        const int rh = l >> 5;
#pragma unroll
        for (int j = 0; j < 8; j++) {
            int row = w * 16 + 2 * j + rh;
            size_t src = ((size_t)(s0 + row) * R_DIM + r) * C_DIM + (size_t)((c1 ^ (row & 7)) * 8);
            async16(xa + (w * 16 + 2 * j) * 256, xnws + src);
        }
    }
    __syncthreads();

    const int lr = l & 15, lk4 = (l >> 4);
    const int colbase = w * 64;
    const int sw = lr & 7;   // row&7 for rows m*16+lr

    float bgv[4], ov[4];
#pragma unroll
    for (int n = 0; n < 4; n++) {
        int col = colbase + n * 16 + lr;
        bgv[n] = bg[col];
        ov[n] = oin[r * 256 + col];
    }

    floatx4 acc[4][4] = {};
#pragma unroll
    for (int kk = 0; kk < 256; kk += 32) {
        const int ch = (((kk >> 3) + lk4) ^ sw) * 8;
        short8 a[4];
#pragma unroll
        for (int m = 0; m < 4; m++)
            a[m] = *reinterpret_cast<const short8*>(xa + (m * 16 + lr) * 256 + ch);
#pragma unroll
        for (int n = 0; n < 4; n++) {
            short8 b = *reinterpret_cast<const short8*>(wgT + (size_t)(colbase + n * 16 + lr) * 256 + kk + lk4 * 8);
#pragma unroll
            for (int m = 0; m < 4; m++)
                acc[m][n] = __builtin_amdgcn_mfma_f32_16x16x32_bf16(a[m], b, acc[m][n], 0, 0, 0);
        }
    }
    __syncthreads();

#pragma unroll
    for (int m = 0; m < 4; m++) {
#pragma unroll
        for (int n = 0; n < 4; n++) {
            int col = colbase + n * 16 + lr;
#pragma unroll
            for (int i = 0; i < 4; i++) {
                int row = m * 16 + lk4 * 4 + i;
                float z = acc[m][n][i] + bgv[n];
                float g = 1.f / (1.f + __expf(-z));
                int idx = row * 256 + (((col >> 3) ^ (row & 7)) * 8) + (col & 7);
                xa[idx] = f2bf(g * ov[n]);
            }
        }
    }
    __syncthreads();

    floatx4 acc2[4][4] = {};
#pragma unroll
    for (int kk = 0; kk < 256; kk += 32) {
        const int ch = (((kk >> 3) + lk4) ^ sw) * 8;
        short8 ah[4];
#pragma unroll
        for (int m = 0; m < 4; m++)
            ah[m] = *reinterpret_cast<const short8*>(xa + (m * 16 + lr) * 256 + ch);
#pragma unroll
        for (int n = 0; n < 4; n++) {
            const size_t boff = (size_t)(colbase + n * 16 + lr) * 256 + kk + lk4 * 8;
            short8 bh = *reinterpret_cast<const short8*>(wfhi + boff);
            short8 bl = *reinterpret_cast<const short8*>(wflo + boff);
#pragma unroll
            for (int m = 0; m < 4; m++) {
                acc2[m][n] = __builtin_amdgcn_mfma_f32_16x16x32_bf16(ah[m], bh, acc2[m][n], 0, 0, 0);
                acc2[m][n] = __builtin_amdgcn_mfma_f32_16x16x32_bf16(ah[m], bl, acc2[m][n], 0, 0, 0);
            }
        }
    }

#pragma unroll
    for (int n = 0; n < 4; n++) {
        int col = colbase + n * 16 + lr;
        float bfc = bfv[col];
#pragma unroll
        for (int m = 0; m < 4; m++) {
#pragma unroll
            for (int i = 0; i < 4; i++) {
                int row = m * 16 + lk4 * 4 + i;
                out[((size_t)(s0 + row) * R_DIM + r) * C_DIM + col] = acc2[m][n][i] + bfc;
            }
        }
    }
}

extern "C" void kernel_launch(void* const* d_in, const int* in_sizes, int n_in,
                              void* d_out, int out_size, void* d_ws, size_t ws_size,
                              hipStream_t stream) {
    const float* x1   = (const float*)d_in[0];
    const float* mask = (const float*)d_in[1];
    const float* lns  = (const float*)d_in[2];
    const float* lnb  = (const float*)d_in[3];
    const float* Wq   = (const float*)d_in[4];
    const float* Wk   = (const float*)d_in[5];
    const float* Wv   = (const float*)d_in[6];
    const float* Wg   = (const float*)d_in[7];
    const float* bg   = (const float*)d_in[8];
    const float* Wf   = (const float*)d_in[9];
    const float* bfv  = (const float*)d_in[10];

    char* ws = (char*)d_ws;
    unsigned short* wgT  = (unsigned short*)(ws);                 // 128 KB
    unsigned short* wfhi = (unsigned short*)(ws + 131072);        // 128 KB
    unsigned short* wflo = (unsigned short*)(ws + 262144);        // 128 KB
    unsigned short* wkvT = (unsigned short*)(ws + 393216);        // 32 KB
    float* qsum = (float*)(ws + 425984);                          // 8 MB
    float* msum = (float*)(ws + 425984 + 8388608);                // 32 KB
    float* oo   = (float*)(ws + 425984 + 8388608 + 32768);        // 512 KB
    unsigned short* xnws = (unsigned short*)(ws + XN_OFF);        // 256 MB (if present)
    // kv scratch lives in d_out (537 MB); K3 overwrites d_out only after K2
    // has consumed kv (same stream => ordered).
    unsigned short* kv = (unsigned short*)d_out;
    float* out = (float*)d_out;

    const bool big_ws = ws_size >= (size_t)XN_OFF + (size_t)XN_BYTES;

    prep_kernel<<<256, 256, 0, stream>>>(Wk, Wv, Wg, Wf, wgT, wfhi, wflo, wkvT);
    if (big_ws) {
        k1_kernel<1><<<dim3(SB, R_DIM), 256, 0, stream>>>(x1, mask, lns, lnb, wkvT, kv, qsum, msum, xnws);
        k2_kernel<<<R_DIM, 256, 0, stream>>>(mask, Wq, qsum, msum, kv, oo);
        k3c_kernel<<<dim3(SB, R_DIM), 256, 0, stream>>>(xnws, wgT, wfhi, wflo, oo, bg, bfv, out);
    } else {
        k1_kernel<0><<<dim3(SB, R_DIM), 256, 0, stream>>>(x1, mask, lns, lnb, wkvT, kv, qsum, msum, nullptr);
        k2_kernel<<<R_DIM, 256, 0, stream>>>(mask, Wq, qsum, msum, kv, oo);
        k3r_kernel<<<dim3(SB, R_DIM), 256, 0, stream>>>(x1, lns, lnb, wgT, wfhi, wflo, oo, bg, bfv, out);
    }
}